// Round 8
// baseline (4875.241 us; speedup 1.0000x reference)
//
#include <hip/hip_runtime.h>
#include <math.h>

#define BB 32
#define NNODE 512
#define TIN 12
#define CCH 32
#define NH 4
#define DDIM 32
#define NL 8
#define SKC 256
#define ENDC 512
#define ODIM 12
#define RFP 13

typedef __attribute__((ext_vector_type(8))) short bf16x8;
typedef __attribute__((ext_vector_type(4))) float f32x4;

__device__ __forceinline__ float sigmoidf_(float x){ return 1.0f/(1.0f+expf(-x)); }
__device__ __forceinline__ unsigned short f2bf(float f){
  unsigned u = __float_as_uint(f);
  u += 0x7FFFu + ((u >> 16) & 1u);
  return (unsigned short)(u >> 16);
}
__device__ __forceinline__ float bf2f(unsigned short h){
  return __uint_as_float(((unsigned)h) << 16);
}
__device__ __forceinline__ void gload16(const void* g, void* l){
  __builtin_amdgcn_global_load_lds(
      (const __attribute__((address_space(1))) void*)g,
      (__attribute__((address_space(3))) void*)l, 16, 0, 0);
}

// ---------------- feature -> l, r ----------------
__global__ void k_feat_lr(const float* __restrict__ input, const float* __restrict__ emb,
                          const float* __restrict__ embds_w, const float* __restrict__ embds_b,
                          const float* __restrict__ wl_w, const float* __restrict__ wl_b,
                          const float* __restrict__ wr_w, const float* __restrict__ wr_b,
                          float* __restrict__ lbuf, float* __restrict__ rbuf){
  int bn = blockIdx.x;          // b*N + n
  int b = bn >> 9, n = bn & 511;
  int j = threadIdx.x;          // 0..127
  __shared__ float f[TIN];
  if (j < TIN){
    float s = 0.f;
    for (int t = 0; t < TIN; ++t) s += input[(b*TIN + t)*NNODE + n] * embds_w[t];
    f[j] = s + embds_b[0] + emb[n*TIN + j];
  }
  __syncthreads();
  float lv = wl_b[j], rv = wr_b[j];
  for (int t = 0; t < TIN; ++t){
    float ft = f[t];
    lv += ft * wl_w[t*128 + j];
    rv += ft * wr_w[t*128 + j];
  }
  int h = j >> 5, d = j & 31;
  int o = ((b*NH + h)*NNODE + n)*DDIM + d;
  lbuf[o] = lv; rbuf[o] = rv;
}

// ---------------- att = l r^T / sqrt(32), 32x32 tiles ----------------
__global__ __launch_bounds__(256) void k_att(const float* __restrict__ lbuf,
                      const float* __restrict__ rbuf, float* __restrict__ att){
  int bh = blockIdx.z;
  int n0 = blockIdx.y * 32, m0 = blockIdx.x * 32;
  int tid = threadIdx.x;
  int tx = tid & 31, ty = tid >> 5;   // 8 row-groups
  __shared__ float Ls[32][33], Rs[32][33];
  const float* lb = lbuf + (size_t)bh*NNODE*DDIM;
  const float* rb = rbuf + (size_t)bh*NNODE*DDIM;
  for (int i = tid; i < 1024; i += 256){
    int r = i >> 5, c = i & 31;
    Ls[r][c] = lb[(n0+r)*DDIM + c];
    Rs[r][c] = rb[(m0+r)*DDIM + c];
  }
  __syncthreads();
  float acc[4] = {0.f,0.f,0.f,0.f};
  for (int d = 0; d < 32; ++d){
    float rv = Rs[tx][d];
    #pragma unroll
    for (int j = 0; j < 4; ++j) acc[j] += Ls[ty + 8*j][d] * rv;
  }
  #pragma unroll
  for (int j = 0; j < 4; ++j)
    att[((size_t)bh*NNODE + n0+ty+8*j)*NNODE + m0 + tx] = acc[j] / sqrtf(32.0f);
}

// -------- per-WAVE exact top-k radix select + softmax; bf16 out in place --------
__global__ __launch_bounds__(256) void k_topk_softmax(float* __restrict__ att){
  __shared__ int hist[4*256];
  int tid = threadIdx.x;
  int wid = tid >> 6, lane = tid & 63;
  int row = blockIdx.x*4 + wid;         // (b*H + h)*N + n
  int h = (row >> 9) & 3;
  int k = (h==0)?10:(h==1)?20:(h==2)?40:500;
  float* rp = att + (size_t)row * NNODE;
  int* hh = hist + wid*256;
  float v[8]; unsigned a[8];
  #pragma unroll
  for (int j = 0; j < 8; ++j){
    v[j] = rp[j*64 + lane];
    unsigned u = __float_as_uint(v[j]);
    a[j] = (u & 0x80000000u) ? ~u : (u | 0x80000000u);
  }
  float m = v[0];
  #pragma unroll
  for (int j = 1; j < 8; ++j) m = fmaxf(m, v[j]);
  for (int off = 32; off; off >>= 1) m = fmaxf(m, __shfl_down(m, off, 64));
  float mx = __shfl(m, 0, 64);
  unsigned pfx = 0u; int kr = k;
  for (int rnd = 0; rnd < 4; ++rnd){
    int sh = 24 - rnd*8;
    #pragma unroll
    for (int i = 0; i < 4; ++i) hh[lane*4+i] = 0;
    __builtin_amdgcn_wave_barrier();
    #pragma unroll
    for (int j = 0; j < 8; ++j){
      bool c = (rnd == 0) || ((a[j] >> (sh+8)) == (pfx >> (sh+8)));
      if (c) atomicAdd(&hh[(a[j] >> sh) & 255], 1);
    }
    __builtin_amdgcn_wave_barrier();
    asm volatile("s_waitcnt lgkmcnt(0)" ::: "memory");
    int h0 = hh[lane*4], h1 = hh[lane*4+1], h2 = hh[lane*4+2], h3 = hh[lane*4+3];
    int s3 = h3, s2 = h2+s3, s1 = h1+s2, s0 = h0+s1;
    int t = s0;
    #pragma unroll
    for (int off = 1; off < 64; off <<= 1){
      int y = __shfl_down(t, off, 64);
      if (lane + off < 64) t += y;
    }
    int Asuf = __shfl_down(t, 1, 64);
    if (lane == 63) Asuf = 0;
    int cs0 = s0+Asuf, cs1 = s1+Asuf, cs2 = s2+Asuf, cs3 = s3+Asuf;
    int found = 0, dloc = 0, krloc = 0;
    if (cs0 >= kr && cs0-h0 < kr){ found=1; dloc=lane*4+0; krloc = kr-(cs0-h0); }
    if (cs1 >= kr && cs1-h1 < kr){ found=1; dloc=lane*4+1; krloc = kr-(cs1-h1); }
    if (cs2 >= kr && cs2-h2 < kr){ found=1; dloc=lane*4+2; krloc = kr-(cs2-h2); }
    if (cs3 >= kr && cs3-h3 < kr){ found=1; dloc=lane*4+3; krloc = kr-(cs3-h3); }
    unsigned long long msk = __ballot(found);
    int src = __ffsll((unsigned long long)msk) - 1;
    int db = __shfl(dloc, src, 64);
    kr = __shfl(krloc, src, 64);
    pfx = pfx | ((unsigned)db << sh);
  }
  unsigned uth = pfx; int neq = kr;   // ties kept, lowest index first
  unsigned long long em[8];
  #pragma unroll
  for (int j = 0; j < 8; ++j) em[j] = __ballot(a[j] == uth);
  int pcum[8]; int run = 0;
  #pragma unroll
  for (int j = 0; j < 8; ++j){ pcum[j] = run; run += (int)__popcll(em[j]); }
  unsigned long long below = (1ull << lane) - 1ull;
  float e[8]; float ssum = 0.f;
  #pragma unroll
  for (int j = 0; j < 8; ++j){
    bool kp = a[j] > uth;
    if (!kp && a[j] == uth){
      int rank = pcum[j] + (int)__popcll(em[j] & below);
      kp = rank < neq;
    }
    e[j] = kp ? expf(v[j] - mx) : 0.f;
    ssum += e[j];
  }
  for (int off = 32; off; off >>= 1) ssum += __shfl_down(ssum, off, 64);
  float tot = __shfl(ssum, 0, 64);
  unsigned short* rp16 = (unsigned short*)rp;
  #pragma unroll
  for (int j = 0; j < 8; ++j) rp16[j*64 + lane] = f2bf(e[j] / tot);
}

// ------- transpose dynBf (bf16 rows, stride 1024 shorts) -> dynT (bf16 [bs][w][v]) -------
__global__ __launch_bounds__(256) void k_transpose_dyn(const unsigned short* __restrict__ dynBf,
                                                       unsigned short* __restrict__ dynT){
  int bs = blockIdx.z;
  int v0 = blockIdx.x*64, w0 = blockIdx.y*64;
  __shared__ unsigned short Ts[64][66];
  const unsigned short* S = dynBf + (size_t)bs*NNODE*1024;
  unsigned short* D = dynT + (size_t)bs*NNODE*NNODE;
  int tid = threadIdx.x;
  for (int i = tid; i < 4096; i += 256){
    int r = i >> 6, c = i & 63;
    Ts[r][c] = S[(size_t)(v0+r)*1024 + w0 + c];
  }
  __syncthreads();
  for (int i = tid; i < 4096; i += 256){
    int r = i >> 6, c = i & 63;
    D[(size_t)(w0+r)*NNODE + v0 + c] = Ts[c][r];
  }
}

// ---------------- supT: transpose s0, s1 into blocks 0, 2 ----------------
__global__ __launch_bounds__(256) void k_supT_copy(const float* __restrict__ supports,
                                                   unsigned short* __restrict__ supT){
  int w = blockIdx.z;                  // 0 -> s0 (block 0), 1 -> s1 (block 2)
  int v0 = blockIdx.x*64, n0 = blockIdx.y*64;
  __shared__ float Ts[64][65];
  const float* S = supports + (size_t)w*NNODE*NNODE;
  int tid = threadIdx.x;
  for (int i = tid; i < 4096; i += 256){
    int r = i >> 6, c = i & 63;
    Ts[r][c] = S[(size_t)(v0+r)*NNODE + n0 + c];
  }
  __syncthreads();
  for (int i = tid; i < 4096; i += 256){
    int r = i >> 6, c = i & 63;
    supT[((size_t)(2*w)*NNODE + n0 + r)*NNODE + v0 + c] = f2bf(Ts[c][r]);
  }
}

// ---------------- supT squares: s@s, transposed store into blocks 1, 3 ----------------
__global__ __launch_bounds__(256) void k_supT_sq(const float* __restrict__ supports,
                                                 unsigned short* __restrict__ supT){
  int which = blockIdx.z;              // 0 -> s0^2 (block 1), 1 -> s1^2 (block 3)
  const float* A = supports + (size_t)which*NNODE*NNODE;
  int w0 = blockIdx.x * 32, v0 = blockIdx.y * 32;
  int tid = threadIdx.x;
  int tx = tid & 31, tyg = tid >> 5;
  __shared__ float As[32][33], Bs[32][33], Cs[32][33];
  float acc[4] = {0.f,0.f,0.f,0.f};
  for (int k0 = 0; k0 < NNODE; k0 += 32){
    int lc = tid >> 3, lu0 = (tid & 7) * 4;
    __syncthreads();
    for (int u = 0; u < 4; ++u){
      As[lc][lu0+u] = A[(size_t)(v0+lc)*NNODE + k0 + lu0 + u];
      Bs[lc][lu0+u] = A[(size_t)(k0+lc)*NNODE + w0 + lu0 + u];
    }
    __syncthreads();
    for (int u = 0; u < 32; ++u){
      float bw = Bs[u][tx];
      #pragma unroll
      for (int j = 0; j < 4; ++j) acc[j] += As[tyg + 8*j][u] * bw;
    }
  }
  __syncthreads();
  #pragma unroll
  for (int j = 0; j < 4; ++j) Cs[tyg + 8*j][tx] = acc[j];   // Cs[v_local][w_local]
  __syncthreads();
  for (int i = tid; i < 1024; i += 256){
    int wl = i >> 5, vl = i & 31;
    supT[((size_t)(2*which+1)*NNODE + w0 + wl)*NNODE + v0 + vl] = f2bf(Cs[vl][wl]);
  }
}

// ---------------- x0 = start conv on left-padded input ----------------
__global__ void k_make_x0(const float* __restrict__ input, const float* __restrict__ start_w,
                          const float* __restrict__ start_b, float* __restrict__ x0){
  int idx = blockIdx.x*256 + threadIdx.x;
  const int total = BB*RFP*CCH*NNODE;
  if (idx >= total) return;
  int n = idx & 511;
  int rest = idx >> 9;
  int c = rest & 31; rest >>= 5;
  int t = rest % RFP;
  int b = rest / RFP;
  float v = (t == 0) ? 0.f : input[((size_t)b*TIN + (t-1))*NNODE + n];
  x0[idx] = start_w[c] * v + start_b[c];
}

// ------- dilated conv + tanh*sigmoid gate -> bf16 act (register-resident, no LDS) -------
__global__ __launch_bounds__(256) void k_dconv_act(const float* __restrict__ x,
      const float* __restrict__ fw, const float* __restrict__ fb,
      const float* __restrict__ gw, const float* __restrict__ gb,
      unsigned short* __restrict__ out, int Tin, int Tp, int dil){
  // grid: (8, Tp, B); thread owns one n, 8 output channels (cg wave-uniform)
  int n0 = blockIdx.x * 64;
  int t = blockIdx.y;
  int b = blockIdx.z;
  int tid = threadIdx.x;
  int lane = tid & 63, cg = tid >> 6;
  int n = n0 + lane;
  const float* xb0 = x + ((size_t)(b*Tin + t)*CCH)*NNODE + n;
  const float* xb1 = xb0 + (size_t)dil*CCH*NNODE;
  float x0[32], x1[32];
  #pragma unroll
  for (int c = 0; c < 32; ++c){ x0[c] = xb0[c*NNODE]; x1[c] = xb1[c*NNODE]; }
  float F[8], G[8];
  #pragma unroll
  for (int j = 0; j < 8; ++j){ int c = cg*8 + j; F[j] = fb[c]; G[j] = gb[c]; }
  #pragma unroll
  for (int cp = 0; cp < 32; ++cp){
    float a = x0[cp], bv = x1[cp];
    #pragma unroll
    for (int j = 0; j < 8; ++j){
      int c = cg*8 + j;
      F[j] += a * fw[c*64 + cp*2] + bv * fw[c*64 + cp*2 + 1];
      G[j] += a * gw[c*64 + cp*2] + bv * gw[c*64 + cp*2 + 1];
    }
  }
  unsigned short* ob = out + ((size_t)(b*Tp + t)*CCH)*NNODE + n;
  #pragma unroll
  for (int j = 0; j < 8; ++j){
    int c = cg*8 + j;
    ob[c*NNODE] = f2bf(tanhf(F[j]) * sigmoidf_(G[j]));
  }
}

// ---------------- skip accumulation at last time slice (bf16 act) ----------------
__global__ __launch_bounds__(256) void k_skip_accum(const unsigned short* __restrict__ act,
     const float* __restrict__ sw, const float* __restrict__ sb,
     float* __restrict__ skip, int Tp, int init){
  int n0 = blockIdx.x * 64;
  int e0 = blockIdx.y * 32;
  int b = blockIdx.z;
  int tid = threadIdx.x;
  int lane = tid & 63, eg = tid >> 6;
  __shared__ float Xs[32][64];
  const unsigned short* ab = act + ((size_t)(b*Tp + Tp-1)*CCH)*NNODE;
  for (int i = tid; i < 2048; i += 256){
    int c = i >> 6, nn2 = i & 63;
    Xs[c][nn2] = bf2f(ab[c*NNODE + n0 + nn2]);
  }
  __syncthreads();
  float acc[8];
  #pragma unroll
  for (int j = 0; j < 8; ++j) acc[j] = sb[e0 + eg*8 + j];
  for (int c = 0; c < 32; ++c){
    float xv = Xs[c][lane];
    #pragma unroll
    for (int j = 0; j < 8; ++j) acc[j] += sw[(e0 + eg*8 + j)*CCH + c] * xv;
  }
  #pragma unroll
  for (int j = 0; j < 8; ++j){
    int e = e0 + eg*8 + j;
    float* dst = &skip[((size_t)b*SKC + e)*NNODE + n0 + lane];
    *dst = init ? acc[j] : (*dst + acc[j]);
  }
}

// ------- fused GCN GEMM: Y = A*BT (K=512, B rows = (s,n)); epilogue mixes channels -------
// out[o,n] = bias[o] + sum_c Wx[o,c]*A[c,n] + sum_{s,c} Ws[o,c]*Y[c,(s,n)]
// dyn mode (outBf): write bf16 R.  sup mode (outF): +residual, *bn -> fp32 next-x.
__global__ __launch_bounds__(256) void k_gcn_gemm(
    const unsigned short* __restrict__ A, const unsigned short* __restrict__ BT,
    const float* __restrict__ w, const float* __restrict__ bias,
    unsigned short* __restrict__ outBf, float* __restrict__ outF,
    const float* __restrict__ res, const float* __restrict__ bng,
    const float* __restrict__ bnb, int Tp, int dil, long long bStride){
  __shared__ short smem[16384 + 5376];   // As(8192) Bs(8192) | Wcat(5376); Tt reuses As
  short* AsL = smem;
  short* BsL = smem + 8192;
  short* Wc  = smem + 16384;
  short* Tt  = smem;                     // 32*168 = 5376 <= 8192
  int tid = threadIdx.x;
  int b = blockIdx.z;
  int n032 = blockIdx.x * 32;
  int t0 = blockIdx.y * 4;
  int Mb = Tp * 32;
  int rowBase = b*Mb + blockIdx.y*128;
  const unsigned short* Bb = BT + (size_t)b * bStride;
  int wid = tid >> 6, lane = tid & 63;
  int wm = wid >> 1, wn = wid & 1;
  int l15 = lane & 15, l4 = lane >> 4;
  // stage Wcat[o][k]: k<128 -> w[o][32+k] (support weights), k>=128 -> w[o][k-128] (Wx)
  for (int i = tid; i < 5120; i += 256){
    int o = i / 160, kk = i - o*160;
    Wc[o*168 + kk] = (short)f2bf(w[o*160 + ((kk < 128) ? (32 + kk) : (kk - 128))]);
  }
  f32x4 acc[4][4];
  #pragma unroll
  for (int mf = 0; mf < 4; ++mf)
    #pragma unroll
    for (int nf = 0; nf < 4; ++nf)
      acc[mf][nf] = (f32x4){0.f, 0.f, 0.f, 0.f};
  for (int k0 = 0; k0 < 512; k0 += 64){
    __syncthreads();
    #pragma unroll
    for (int it = 0; it < 4; ++it){
      int r = it*32 + (tid>>3), g = tid & 7;
      gload16(A + (size_t)(rowBase + r)*512 + k0 + ((g ^ (r&7))<<3), AsL + r*64 + (g<<3));
      int s = r >> 5, nl = r & 31;
      gload16(Bb + (size_t)((s<<9) + n032 + nl)*512 + k0 + ((g ^ (r&7))<<3), BsL + r*64 + (g<<3));
    }
    __syncthreads();
    #pragma unroll
    for (int ks = 0; ks < 2; ++ks){
      bf16x8 af[4], bfr[4];
      #pragma unroll
      for (int mf = 0; mf < 4; ++mf){
        int rr = wm*64 + mf*16 + l15;
        af[mf] = *(const bf16x8*)(AsL + rr*64 + (((ks*4 + l4) ^ (rr & 7)) << 3));
      }
      #pragma unroll
      for (int nf = 0; nf < 4; ++nf){
        int rr = wn*64 + nf*16 + l15;
        bfr[nf] = *(const bf16x8*)(BsL + rr*64 + (((ks*4 + l4) ^ (rr & 7)) << 3));
      }
      #pragma unroll
      for (int mf = 0; mf < 4; ++mf)
        #pragma unroll
        for (int nf = 0; nf < 4; ++nf)
          acc[mf][nf] = __builtin_amdgcn_mfma_f32_16x16x32_bf16(af[mf], bfr[nf], acc[mf][nf], 0, 0, 0);
    }
  }
  const float inv = 1.0f / sqrtf(1.0f + 1e-5f);
  for (int t = 0; t < 4; ++t){
    __syncthreads();   // As/Bs (or prev Tt) free
    if (wm == (t >> 1)){
      #pragma unroll
      for (int mf2 = 0; mf2 < 2; ++mf2){
        int mf = (t & 1)*2 + mf2;
        #pragma unroll
        for (int nf = 0; nf < 4; ++nf){
          int c128 = wn*64 + nf*16 + l15;
          int s = c128 >> 5, nl = c128 & 31;
          #pragma unroll
          for (int r = 0; r < 4; ++r){
            int cROW = mf2*16 + l4*4 + r;
            Tt[nl*168 + s*32 + cROW] = (short)f2bf(acc[mf][nf][r]);
          }
        }
      }
    }
    // X^T chunk: cols 128..159 = A[c][n] transposed (the Wx term's input)
    for (int i = tid; i < 1024; i += 256){
      int c = i >> 5, nl = i & 31;
      Tt[nl*168 + 128 + c] =
        (short)A[(size_t)(b*Mb + (t0+t)*32 + c)*512 + n032 + nl];
    }
    __syncthreads();
    f32x4 am = (f32x4){0.f,0.f,0.f,0.f};
    #pragma unroll
    for (int ks = 0; ks < 5; ++ks){
      bf16x8 af = *(const bf16x8*)(Wc + (wm*16 + l15)*168 + ks*32 + l4*8);
      bf16x8 bf = *(const bf16x8*)(Tt + (wn*16 + l15)*168 + ks*32 + l4*8);
      am = __builtin_amdgcn_mfma_f32_16x16x32_bf16(af, bf, am, 0, 0, 0);
    }
    if (t0 + t < Tp){
      int btG = b*Tp + t0 + t;
      #pragma unroll
      for (int r = 0; r < 4; ++r){
        int o = wm*16 + l4*4 + r;
        int nl = wn*16 + l15;
        size_t oidx = (size_t)(btG*32 + o)*512 + n032 + nl;
        float val = am[r] + bias[o];
        if (outBf){
          outBf[oidx] = f2bf(val);
        } else {
          float resv = res[(size_t)((b*(Tp+dil) + t0 + t + dil)*32 + o)*512 + n032 + nl];
          outF[oidx] = (val + resv) * (bng[o]*inv) + bnb[o];
        }
      }
    }
  }
}

// ------- plain bf16 MFMA GEMM (used for end1): Y[m,n] = A[m,v]*BT[n,v] -------
__global__ __launch_bounds__(256) void k_gemm(
    const unsigned short* __restrict__ A, const unsigned short* __restrict__ BT,
    unsigned short* __restrict__ Y, int Mb, long long bStride,
    int K, int Ystride, int relu){
  __shared__ short As[128][64];
  __shared__ short Bs[128][64];
  int tid = threadIdx.x;
  int n0 = blockIdx.x * 128;
  int rowBase = blockIdx.z * Mb + blockIdx.y * 128;
  int rowEnd  = blockIdx.z * Mb + Mb;
  const unsigned short* Bb = BT + (size_t)blockIdx.z * bStride;
  int wid = tid >> 6, lane = tid & 63;
  int wm = wid >> 1, wn = wid & 1;
  int l15 = lane & 15, l4 = lane >> 4;
  f32x4 acc[4][4];
  #pragma unroll
  for (int mf = 0; mf < 4; ++mf)
    #pragma unroll
    for (int nf = 0; nf < 4; ++nf)
      acc[mf][nf] = (f32x4){0.f, 0.f, 0.f, 0.f};
  for (int k0 = 0; k0 < K; k0 += 64){
    __syncthreads();
    #pragma unroll
    for (int it = 0; it < 4; ++it){
      int r = it*32 + (tid>>3), g = tid & 7;
      gload16(A + (size_t)(rowBase + r)*K + k0 + ((g ^ (r&7))<<3), &As[r][g<<3]);
      gload16(Bb + (size_t)(n0 + r)*K + k0 + ((g ^ (r&7))<<3), &Bs[r][g<<3]);
    }
    __syncthreads();
    #pragma unroll
    for (int ks = 0; ks < 2; ++ks){
      bf16x8 af[4], bfr[4];
      #pragma unroll
      for (int mf = 0; mf < 4; ++mf){
        int r = wm*64 + mf*16 + l15;
        af[mf] = *(const bf16x8*)&As[r][(((ks*4 + l4) ^ (r & 7)) << 3)];
      }
      #pragma unroll
      for (int nf = 0; nf < 4; ++nf){
        int r = wn*64 + nf*16 + l15;
        bfr[nf] = *(const bf16x8*)&Bs[r][(((ks*4 + l4) ^ (r & 7)) << 3)];
      }
      #pragma unroll
      for (int mf = 0; mf < 4; ++mf)
        #pragma unroll
        for (int nf = 0; nf < 4; ++nf)
          acc[mf][nf] = __builtin_amdgcn_mfma_f32_16x16x32_bf16(af[mf], bfr[nf], acc[mf][nf], 0, 0, 0);
    }
  }
  #pragma unroll
  for (int mf = 0; mf < 4; ++mf){
    #pragma unroll
    for (int nf = 0; nf < 4; ++nf){
      #pragma unroll
      for (int r = 0; r < 4; ++r){
        int row = rowBase + wm*64 + mf*16 + l4*4 + r;
        if (row < rowEnd){
          int col = n0 + wn*64 + nf*16 + l15;
          float v = acc[mf][nf][r];
          if (relu) v = v > 0.f ? v : 0.f;
          Y[(size_t)row*Ystride + col] = f2bf(v);
        }
      }
    }
  }
}

// ---------------- skip -> relu -> bf16 transposed [(b,n), e] ----------------
__global__ __launch_bounds__(256) void k_skipT(const float* __restrict__ skip,
                                               unsigned short* __restrict__ skT){
  int b = blockIdx.z, e0 = blockIdx.y*64, n0 = blockIdx.x*64;
  __shared__ float Ts[64][65];
  int tid = threadIdx.x;
  for (int i = tid; i < 4096; i += 256){
    int r = i >> 6, c = i & 63;
    Ts[r][c] = skip[((size_t)b*SKC + e0 + r)*NNODE + n0 + c];
  }
  __syncthreads();
  for (int i = tid; i < 4096; i += 256){
    int r = i >> 6, c = i & 63;     // r = n-local, c = e-local
    float v = Ts[c][r];
    skT[((size_t)b*NNODE + n0 + r)*SKC + e0 + c] = f2bf(v > 0.f ? v : 0.f);
  }
}

// ---------------- fp32 -> bf16 weight converts ----------------
__global__ void k_cvt(const float* __restrict__ src, unsigned short* __restrict__ dst, int n){
  int i = blockIdx.x*256 + threadIdx.x;
  if (i < n) dst[i] = f2bf(src[i]);
}
__global__ void k_cvt_e2(const float* __restrict__ e2w, unsigned short* __restrict__ dst){
  int i = blockIdx.x*256 + threadIdx.x;   // 16*512
  if (i < 16*ENDC){
    int o = i >> 9;
    dst[i] = (o < ODIM) ? f2bf(e2w[(size_t)o*ENDC + (i & 511)]) : (unsigned short)0;
  }
}

// ---------------- end2: out[b,o,n] = e2b[o] + hid[(b,n),:]·e2w[o,:] ----------------
__global__ __launch_bounds__(256) void k_end2(const unsigned short* __restrict__ hid,
    const unsigned short* __restrict__ e2wB, const float* __restrict__ e2b,
    float* __restrict__ out){
  int rowBase = blockIdx.x * 64;
  int tid = threadIdx.x;
  int lane = tid & 63, w = tid >> 6;
  int l15 = lane & 15, l4 = lane >> 4;
  __shared__ unsigned short e2s[16][520];
  __shared__ float Cs[16][68];
  for (int i = tid; i < 4096; i += 256){
    int r = i >> 8, c2 = (i & 255) * 2;
    *(unsigned*)&e2s[r][c2] = *(const unsigned*)&e2wB[(size_t)r*ENDC + c2];
  }
  __syncthreads();
  f32x4 acc = (f32x4){0.f,0.f,0.f,0.f};
  const unsigned short* Ab = hid + (size_t)(rowBase + w*16 + l15)*ENDC;
  #pragma unroll
  for (int kk = 0; kk < 16; ++kk){
    bf16x8 af = *(const bf16x8*)(Ab + kk*32 + l4*8);
    bf16x8 bf = *(const bf16x8*)&e2s[l15][kk*32 + l4*8];
    acc = __builtin_amdgcn_mfma_f32_16x16x32_bf16(af, bf, acc, 0, 0, 0);
  }
  #pragma unroll
  for (int r = 0; r < 4; ++r)
    Cs[l15][w*16 + l4*4 + r] = acc[r];
  __syncthreads();
  for (int i = tid; i < ODIM*64; i += 256){
    int o = i >> 6, nl = i & 63;
    int gr = rowBase + nl;
    int b = gr >> 9, n = gr & 511;
    out[((size_t)(b*ODIM + o))*NNODE + n] = Cs[o][nl] + e2b[o];
  }
}

extern "C" void kernel_launch(void* const* d_in, const int* in_sizes, int n_in,
                              void* d_out, int out_size, void* d_ws, size_t ws_size,
                              hipStream_t stream){
  const float* input   = (const float*)d_in[0];
  const float* supports= (const float*)d_in[1];
  const float* emb     = (const float*)d_in[2];
  const float* embds_w = (const float*)d_in[3];
  const float* embds_b = (const float*)d_in[4];
  const float* wl_w    = (const float*)d_in[5];
  const float* wl_b    = (const float*)d_in[6];
  const float* wr_w    = (const float*)d_in[7];
  const float* wr_b    = (const float*)d_in[8];
  const float* start_w = (const float*)d_in[9];
  const float* start_b = (const float*)d_in[10];
  const float* filter_w= (const float*)d_in[11];
  const float* filter_b= (const float*)d_in[12];
  const float* gate_w  = (const float*)d_in[13];
  const float* gate_b  = (const float*)d_in[14];
  const float* skip_w  = (const float*)d_in[15];
  const float* skip_b  = (const float*)d_in[16];
  const float* bn_g    = (const float*)d_in[17];
  const float* bn_b    = (const float*)d_in[18];
  const float* gconv_w = (const float*)d_in[19];
  const float* gconv_b = (const float*)d_in[20];
  const float* dyn_w   = (const float*)d_in[21];
  const float* dyn_b   = (const float*)d_in[22];
  const float* end1_w  = (const float*)d_in[23];
  const float* end1_b  = (const float*)d_in[24];
  const float* end2_w  = (const float*)d_in[25];
  const float* end2_b  = (const float*)d_in[26];
  float* out = (float*)d_out;

  float* ws = (float*)d_ws;
  // ---- Region R0: 33,554,432 floats. Prologue: fp32 att (becomes bf16 in place).
  //      Loop phase: act | bufP | bufQ | skip | R.
  float* dyn = ws;
  unsigned short* act = (unsigned short*)ws;                 // 3,145,728 floats
  float* bufP = ws + 3145728;                                // 6,815,744
  float* bufQ = ws + 3145728 + 6815744;                      // 6,815,744
  float* skip = ws + 16777216;                               // 4,194,304
  unsigned short* R = (unsigned short*)(ws + 20971520);      // 3,145,728 floats (in old Y region)
  // ---- dynT region: 16,777,216 floats (33,554,432 bf16). Prologue alias: l/r.
  unsigned short* dynT = (unsigned short*)(ws + 33554432);
  float* lbuf = ws + 33554432;                               // 2,097,152 (alias)
  float* rbuf = ws + 33554432 + 2097152;                     // 2,097,152 (alias)
  // ---- supT: 524,288 floats.
  unsigned short* supT = (unsigned short*)(ws + 33554432 + 16777216);
  // ---- end-MLP buffers (used only after the layer loop):
  unsigned short* skT  = (unsigned short*)(ws + 50855936);   // 2,097,152 floats
  unsigned short* hid  = (unsigned short*)(ws + 52953088);   // 4,194,304 floats
  unsigned short* e1wB = (unsigned short*)(ws + 57147392);   //    65,536 floats
  unsigned short* e2wB = (unsigned short*)(ws + 57212928);   //     4,096 floats
  // total: 57,217,024 floats = 228.9 MB (proven-safe)

  hipLaunchKernelGGL(k_feat_lr, dim3(BB*NNODE), dim3(128), 0, stream,
                     input, emb, embds_w, embds_b, wl_w, wl_b, wr_w, wr_b, lbuf, rbuf);
  hipLaunchKernelGGL(k_att, dim3(16, 16, BB*NH), dim3(256), 0, stream, lbuf, rbuf, dyn);
  hipLaunchKernelGGL(k_topk_softmax, dim3(BB*NH*NNODE/4), dim3(256), 0, stream, dyn);
  hipLaunchKernelGGL(k_transpose_dyn, dim3(8, 8, BB*NH), dim3(256), 0, stream,
                     (const unsigned short*)dyn, dynT);
  hipLaunchKernelGGL(k_supT_copy, dim3(8, 8, 2), dim3(256), 0, stream, supports, supT);
  hipLaunchKernelGGL(k_supT_sq, dim3(16, 16, 2), dim3(256), 0, stream, supports, supT);
  {
    int total = BB*RFP*CCH*NNODE;
    hipLaunchKernelGGL(k_make_x0, dim3((total+255)/256), dim3(256), 0, stream,
                       input, start_w, start_b, bufP);
  }

  const int dil_[8] = {1,2,1,2,1,2,1,2};
  int T = RFP;
  float* P = bufP; float* Q = bufQ;
  for (int i = 0; i < NL; ++i){
    int d = dil_[i], Tp = T - d;
    int mT = (Tp*32 + 127)/128;
    hipLaunchKernelGGL(k_dconv_act, dim3(8, Tp, BB), dim3(256), 0, stream,
        P, filter_w + i*2048, filter_b + i*32, gate_w + i*2048, gate_b + i*32,
        act, T, Tp, d);
    hipLaunchKernelGGL(k_skip_accum, dim3(8, 8, BB), dim3(256), 0, stream,
        act, skip_w + i*SKC*CCH, skip_b + i*SKC, skip, Tp, (i==0)?1:0);
    // dyn GCN + mix -> R (bf16)
    hipLaunchKernelGGL(k_gcn_gemm, dim3(16, mT, BB), dim3(256), 0, stream,
        act, dynT, dyn_w + i*5120, dyn_b + i*32,
        R, (float*)nullptr, (const float*)nullptr, (const float*)nullptr,
        (const float*)nullptr, Tp, d, (long long)NH*NNODE*NNODE);
    // sup GCN + mix + residual + bn -> Q (fp32)
    hipLaunchKernelGGL(k_gcn_gemm, dim3(16, mT, BB), dim3(256), 0, stream,
        R, supT, gconv_w + i*5120, gconv_b + i*32,
        (unsigned short*)nullptr, Q, P, bn_g + i*32, bn_b + i*32, Tp, d, 0LL);
    float* tmp = P; P = Q; Q = tmp;
    T = Tp;
  }
  // ---- end MLP: skipT -> MFMA end1 (relu) -> MFMA end2 ----
  hipLaunchKernelGGL(k_skipT, dim3(8, 4, BB), dim3(256), 0, stream, skip, skT);
  hipLaunchKernelGGL(k_cvt, dim3((ENDC*SKC+255)/256), dim3(256), 0, stream,
                     end1_w, e1wB, ENDC*SKC);
  hipLaunchKernelGGL(k_cvt_e2, dim3((16*ENDC+255)/256), dim3(256), 0, stream,
                     end2_w, e2wB);
  hipLaunchKernelGGL(k_gemm, dim3(4, 128, 1), dim3(256), 0, stream,
      skT, e1wB, hid, BB*NNODE, 0LL, 256, 512, 1);
  hipLaunchKernelGGL(k_end2, dim3(256), dim3(256), 0, stream, hid, e2wB, end1_b, out);
}

// Round 9
// 1811.461 us; speedup vs baseline: 2.6913x; 2.6913x over previous
//
#include <hip/hip_runtime.h>
#include <math.h>

#define BB 32
#define NNODE 512
#define TIN 12
#define CCH 32
#define NH 4
#define DDIM 32
#define NL 8
#define SKC 256
#define ENDC 512
#define ODIM 12
#define RFP 13

typedef __attribute__((ext_vector_type(8))) short bf16x8;
typedef __attribute__((ext_vector_type(4))) float f32x4;

__device__ __forceinline__ float sigmoidf_(float x){ return 1.0f/(1.0f+expf(-x)); }
__device__ __forceinline__ unsigned short f2bf(float f){
  unsigned u = __float_as_uint(f);
  u += 0x7FFFu + ((u >> 16) & 1u);
  return (unsigned short)(u >> 16);
}
__device__ __forceinline__ float bf2f(unsigned short h){
  return __uint_as_float(((unsigned)h) << 16);
}
__device__ __forceinline__ void gload16(const void* g, void* l){
  __builtin_amdgcn_global_load_lds(
      (const __attribute__((address_space(1))) void*)g,
      (__attribute__((address_space(3))) void*)l, 16, 0, 0);
}

// ---------------- feature -> l, r ----------------
__global__ void k_feat_lr(const float* __restrict__ input, const float* __restrict__ emb,
                          const float* __restrict__ embds_w, const float* __restrict__ embds_b,
                          const float* __restrict__ wl_w, const float* __restrict__ wl_b,
                          const float* __restrict__ wr_w, const float* __restrict__ wr_b,
                          float* __restrict__ lbuf, float* __restrict__ rbuf){
  int bn = blockIdx.x;          // b*N + n
  int b = bn >> 9, n = bn & 511;
  int j = threadIdx.x;          // 0..127
  __shared__ float f[TIN];
  if (j < TIN){
    float s = 0.f;
    for (int t = 0; t < TIN; ++t) s += input[(b*TIN + t)*NNODE + n] * embds_w[t];
    f[j] = s + embds_b[0] + emb[n*TIN + j];
  }
  __syncthreads();
  float lv = wl_b[j], rv = wr_b[j];
  for (int t = 0; t < TIN; ++t){
    float ft = f[t];
    lv += ft * wl_w[t*128 + j];
    rv += ft * wr_w[t*128 + j];
  }
  int h = j >> 5, d = j & 31;
  int o = ((b*NH + h)*NNODE + n)*DDIM + d;
  lbuf[o] = lv; rbuf[o] = rv;
}

// ---------------- att = l r^T / sqrt(32), 32x32 tiles ----------------
__global__ __launch_bounds__(256) void k_att(const float* __restrict__ lbuf,
                      const float* __restrict__ rbuf, float* __restrict__ att){
  int bh = blockIdx.z;
  int n0 = blockIdx.y * 32, m0 = blockIdx.x * 32;
  int tid = threadIdx.x;
  int tx = tid & 31, ty = tid >> 5;   // 8 row-groups
  __shared__ float Ls[32][33], Rs[32][33];
  const float* lb = lbuf + (size_t)bh*NNODE*DDIM;
  const float* rb = rbuf + (size_t)bh*NNODE*DDIM;
  for (int i = tid; i < 1024; i += 256){
    int r = i >> 5, c = i & 31;
    Ls[r][c] = lb[(n0+r)*DDIM + c];
    Rs[r][c] = rb[(m0+r)*DDIM + c];
  }
  __syncthreads();
  float acc[4] = {0.f,0.f,0.f,0.f};
  for (int d = 0; d < 32; ++d){
    float rv = Rs[tx][d];
    #pragma unroll
    for (int j = 0; j < 4; ++j) acc[j] += Ls[ty + 8*j][d] * rv;
  }
  #pragma unroll
  for (int j = 0; j < 4; ++j)
    att[((size_t)bh*NNODE + n0+ty+8*j)*NNODE + m0 + tx] = acc[j] / sqrtf(32.0f);
}

// -------- per-WAVE exact top-k radix select + softmax; bf16 out in place --------
__global__ __launch_bounds__(256) void k_topk_softmax(float* __restrict__ att){
  __shared__ int hist[4*256];
  int tid = threadIdx.x;
  int wid = tid >> 6, lane = tid & 63;
  int row = blockIdx.x*4 + wid;         // (b*H + h)*N + n
  int h = (row >> 9) & 3;
  int k = (h==0)?10:(h==1)?20:(h==2)?40:500;
  float* rp = att + (size_t)row * NNODE;
  int* hh = hist + wid*256;
  float v[8]; unsigned a[8];
  #pragma unroll
  for (int j = 0; j < 8; ++j){
    v[j] = rp[j*64 + lane];
    unsigned u = __float_as_uint(v[j]);
    a[j] = (u & 0x80000000u) ? ~u : (u | 0x80000000u);
  }
  float m = v[0];
  #pragma unroll
  for (int j = 1; j < 8; ++j) m = fmaxf(m, v[j]);
  for (int off = 32; off; off >>= 1) m = fmaxf(m, __shfl_down(m, off, 64));
  float mx = __shfl(m, 0, 64);
  unsigned pfx = 0u; int kr = k;
  for (int rnd = 0; rnd < 4; ++rnd){
    int sh = 24 - rnd*8;
    #pragma unroll
    for (int i = 0; i < 4; ++i) hh[lane*4+i] = 0;
    __builtin_amdgcn_wave_barrier();
    #pragma unroll
    for (int j = 0; j < 8; ++j){
      bool c = (rnd == 0) || ((a[j] >> (sh+8)) == (pfx >> (sh+8)));
      if (c) atomicAdd(&hh[(a[j] >> sh) & 255], 1);
    }
    __builtin_amdgcn_wave_barrier();
    asm volatile("s_waitcnt lgkmcnt(0)" ::: "memory");
    int h0 = hh[lane*4], h1 = hh[lane*4+1], h2 = hh[lane*4+2], h3 = hh[lane*4+3];
    int s3 = h3, s2 = h2+s3, s1 = h1+s2, s0 = h0+s1;
    int t = s0;
    #pragma unroll
    for (int off = 1; off < 64; off <<= 1){
      int y = __shfl_down(t, off, 64);
      if (lane + off < 64) t += y;
    }
    int Asuf = __shfl_down(t, 1, 64);
    if (lane == 63) Asuf = 0;
    int cs0 = s0+Asuf, cs1 = s1+Asuf, cs2 = s2+Asuf, cs3 = s3+Asuf;
    int found = 0, dloc = 0, krloc = 0;
    if (cs0 >= kr && cs0-h0 < kr){ found=1; dloc=lane*4+0; krloc = kr-(cs0-h0); }
    if (cs1 >= kr && cs1-h1 < kr){ found=1; dloc=lane*4+1; krloc = kr-(cs1-h1); }
    if (cs2 >= kr && cs2-h2 < kr){ found=1; dloc=lane*4+2; krloc = kr-(cs2-h2); }
    if (cs3 >= kr && cs3-h3 < kr){ found=1; dloc=lane*4+3; krloc = kr-(cs3-h3); }
    unsigned long long msk = __ballot(found);
    int src = __ffsll((unsigned long long)msk) - 1;
    int db = __shfl(dloc, src, 64);
    kr = __shfl(krloc, src, 64);
    pfx = pfx | ((unsigned)db << sh);
  }
  unsigned uth = pfx; int neq = kr;   // ties kept, lowest index first
  unsigned long long em[8];
  #pragma unroll
  for (int j = 0; j < 8; ++j) em[j] = __ballot(a[j] == uth);
  int pcum[8]; int run = 0;
  #pragma unroll
  for (int j = 0; j < 8; ++j){ pcum[j] = run; run += (int)__popcll(em[j]); }
  unsigned long long below = (1ull << lane) - 1ull;
  float e[8]; float ssum = 0.f;
  #pragma unroll
  for (int j = 0; j < 8; ++j){
    bool kp = a[j] > uth;
    if (!kp && a[j] == uth){
      int rank = pcum[j] + (int)__popcll(em[j] & below);
      kp = rank < neq;
    }
    e[j] = kp ? expf(v[j] - mx) : 0.f;
    ssum += e[j];
  }
  for (int off = 32; off; off >>= 1) ssum += __shfl_down(ssum, off, 64);
  float tot = __shfl(ssum, 0, 64);
  unsigned short* rp16 = (unsigned short*)rp;
  #pragma unroll
  for (int j = 0; j < 8; ++j) rp16[j*64 + lane] = f2bf(e[j] / tot);
}

// ------- transpose dynBf (bf16 rows, stride 1024 shorts) -> dynT (bf16 [bs][w][v]) -------
__global__ __launch_bounds__(256) void k_transpose_dyn(const unsigned short* __restrict__ dynBf,
                                                       unsigned short* __restrict__ dynT){
  int bs = blockIdx.z;
  int v0 = blockIdx.x*64, w0 = blockIdx.y*64;
  __shared__ unsigned short Ts[64][66];
  const unsigned short* S = dynBf + (size_t)bs*NNODE*1024;
  unsigned short* D = dynT + (size_t)bs*NNODE*NNODE;
  int tid = threadIdx.x;
  for (int i = tid; i < 4096; i += 256){
    int r = i >> 6, c = i & 63;
    Ts[r][c] = S[(size_t)(v0+r)*1024 + w0 + c];
  }
  __syncthreads();
  for (int i = tid; i < 4096; i += 256){
    int r = i >> 6, c = i & 63;
    D[(size_t)(w0+r)*NNODE + v0 + c] = Ts[c][r];
  }
}

// ---------------- supT: transpose s0, s1 into blocks 0, 2 ----------------
__global__ __launch_bounds__(256) void k_supT_copy(const float* __restrict__ supports,
                                                   unsigned short* __restrict__ supT){
  int w = blockIdx.z;                  // 0 -> s0 (block 0), 1 -> s1 (block 2)
  int v0 = blockIdx.x*64, n0 = blockIdx.y*64;
  __shared__ float Ts[64][65];
  const float* S = supports + (size_t)w*NNODE*NNODE;
  int tid = threadIdx.x;
  for (int i = tid; i < 4096; i += 256){
    int r = i >> 6, c = i & 63;
    Ts[r][c] = S[(size_t)(v0+r)*NNODE + n0 + c];
  }
  __syncthreads();
  for (int i = tid; i < 4096; i += 256){
    int r = i >> 6, c = i & 63;
    supT[((size_t)(2*w)*NNODE + n0 + r)*NNODE + v0 + c] = f2bf(Ts[c][r]);
  }
}

// ---------------- supT squares: s@s, transposed store into blocks 1, 3 ----------------
__global__ __launch_bounds__(256) void k_supT_sq(const float* __restrict__ supports,
                                                 unsigned short* __restrict__ supT){
  int which = blockIdx.z;              // 0 -> s0^2 (block 1), 1 -> s1^2 (block 3)
  const float* A = supports + (size_t)which*NNODE*NNODE;
  int w0 = blockIdx.x * 32, v0 = blockIdx.y * 32;
  int tid = threadIdx.x;
  int tx = tid & 31, tyg = tid >> 5;
  __shared__ float As[32][33], Bs[32][33], Cs[32][33];
  float acc[4] = {0.f,0.f,0.f,0.f};
  for (int k0 = 0; k0 < NNODE; k0 += 32){
    int lc = tid >> 3, lu0 = (tid & 7) * 4;
    __syncthreads();
    for (int u = 0; u < 4; ++u){
      As[lc][lu0+u] = A[(size_t)(v0+lc)*NNODE + k0 + lu0 + u];
      Bs[lc][lu0+u] = A[(size_t)(k0+lc)*NNODE + w0 + lu0 + u];
    }
    __syncthreads();
    for (int u = 0; u < 32; ++u){
      float bw = Bs[u][tx];
      #pragma unroll
      for (int j = 0; j < 4; ++j) acc[j] += As[tyg + 8*j][u] * bw;
    }
  }
  __syncthreads();
  #pragma unroll
  for (int j = 0; j < 4; ++j) Cs[tyg + 8*j][tx] = acc[j];   // Cs[v_local][w_local]
  __syncthreads();
  for (int i = tid; i < 1024; i += 256){
    int wl = i >> 5, vl = i & 31;
    supT[((size_t)(2*which+1)*NNODE + w0 + wl)*NNODE + v0 + vl] = f2bf(Cs[vl][wl]);
  }
}

// ---------------- x0 = start conv on left-padded input ----------------
__global__ void k_make_x0(const float* __restrict__ input, const float* __restrict__ start_w,
                          const float* __restrict__ start_b, float* __restrict__ x0){
  int idx = blockIdx.x*256 + threadIdx.x;
  const int total = BB*RFP*CCH*NNODE;
  if (idx >= total) return;
  int n = idx & 511;
  int rest = idx >> 9;
  int c = rest & 31; rest >>= 5;
  int t = rest % RFP;
  int b = rest / RFP;
  float v = (t == 0) ? 0.f : input[((size_t)b*TIN + (t-1))*NNODE + n];
  x0[idx] = start_w[c] * v + start_b[c];
}

// ------- dilated conv + tanh*sigmoid gate -> bf16 act -------
// Block 512 thr = one (b,t); thread owns one n: x in VGPRs, weights LDS-broadcast,
// scalar f/g accumulators (no spillable arrays).
__global__ __launch_bounds__(512) void k_dconv_act(const float* __restrict__ x,
      const float* __restrict__ fw, const float* __restrict__ fb,
      const float* __restrict__ gw, const float* __restrict__ gb,
      unsigned short* __restrict__ out, int Tin, int Tp, int dil){
  int t = blockIdx.x;
  int b = blockIdx.y;
  int n = threadIdx.x;
  __shared__ float2 wf[32][32], wg[32][32];   // [c][cp] = (tap0, tap1)
  for (int i = n; i < 1024; i += 512){
    ((float2*)wf)[i] = ((const float2*)fw)[i];
    ((float2*)wg)[i] = ((const float2*)gw)[i];
  }
  const float* xb0 = x + ((size_t)(b*Tin + t)*CCH)*NNODE + n;
  const float* xb1 = xb0 + (size_t)dil*CCH*NNODE;
  float x0[32], x1[32];
  #pragma unroll
  for (int cp = 0; cp < 32; ++cp){ x0[cp] = xb0[cp*NNODE]; x1[cp] = xb1[cp*NNODE]; }
  __syncthreads();
  unsigned short* ob = out + ((size_t)(b*Tp + t)*CCH)*NNODE + n;
  #pragma unroll 4
  for (int c = 0; c < 32; ++c){
    float f = fb[c], g = gb[c];
    #pragma unroll
    for (int cp = 0; cp < 32; ++cp){
      float2 a = wf[c][cp], bb = wg[c][cp];
      f += x0[cp]*a.x + x1[cp]*a.y;
      g += x0[cp]*bb.x + x1[cp]*bb.y;
    }
    ob[c*NNODE] = f2bf(tanhf(f) * sigmoidf_(g));
  }
}

// ---------------- skip accumulation at last time slice (bf16 act) ----------------
__global__ __launch_bounds__(256) void k_skip_accum(const unsigned short* __restrict__ act,
     const float* __restrict__ sw, const float* __restrict__ sb,
     float* __restrict__ skip, int Tp, int init){
  int n0 = blockIdx.x * 64;
  int e0 = blockIdx.y * 32;
  int b = blockIdx.z;
  int tid = threadIdx.x;
  int lane = tid & 63, eg = tid >> 6;
  __shared__ float Xs[32][64];
  const unsigned short* ab = act + ((size_t)(b*Tp + Tp-1)*CCH)*NNODE;
  for (int i = tid; i < 2048; i += 256){
    int c = i >> 6, nn2 = i & 63;
    Xs[c][nn2] = bf2f(ab[c*NNODE + n0 + nn2]);
  }
  __syncthreads();
  float acc[8];
  #pragma unroll
  for (int j = 0; j < 8; ++j) acc[j] = sb[e0 + eg*8 + j];
  for (int c = 0; c < 32; ++c){
    float xv = Xs[c][lane];
    #pragma unroll
    for (int j = 0; j < 8; ++j) acc[j] += sw[(e0 + eg*8 + j)*CCH + c] * xv;
  }
  #pragma unroll
  for (int j = 0; j < 8; ++j){
    int e = e0 + eg*8 + j;
    float* dst = &skip[((size_t)b*SKC + e)*NNODE + n0 + lane];
    *dst = init ? acc[j] : (*dst + acc[j]);
  }
}

// ------- fused GCN GEMM: Y = A*BT (K=512, B rows = (s,n)); epilogue mixes channels -------
// out[o,n] = bias[o] + sum_c Wx[o,c]*A[c,n] + sum_{s,c} Ws[o,c]*Y[c,(s,n)]
// dyn mode (outBf): write bf16 R.  sup mode (outF): +residual, *bn -> fp32 next-x.
__global__ __launch_bounds__(256) void k_gcn_gemm(
    const unsigned short* __restrict__ A, const unsigned short* __restrict__ BT,
    const float* __restrict__ w, const float* __restrict__ bias,
    unsigned short* __restrict__ outBf, float* __restrict__ outF,
    const float* __restrict__ res, const float* __restrict__ bng,
    const float* __restrict__ bnb, int Tp, int dil, long long bStride){
  __shared__ short smem[16384 + 5376];   // As(8192) Bs(8192) | Wcat(5376); Tt reuses As
  short* AsL = smem;
  short* BsL = smem + 8192;
  short* Wc  = smem + 16384;
  short* Tt  = smem;                     // 32*168 = 5376 <= 8192
  int tid = threadIdx.x;
  int b = blockIdx.z;
  int n032 = blockIdx.x * 32;
  int t0 = blockIdx.y * 4;
  int Mb = Tp * 32;
  int rowBase = b*Mb + blockIdx.y*128;
  const unsigned short* Bb = BT + (size_t)b * bStride;
  int wid = tid >> 6, lane = tid & 63;
  int wm = wid >> 1, wn = wid & 1;
  int l15 = lane & 15, l4 = lane >> 4;
  // stage Wcat[o][k]: k<128 -> w[o][32+k] (support weights), k>=128 -> w[o][k-128] (Wx)
  for (int i = tid; i < 5120; i += 256){
    int o = i / 160, kk = i - o*160;
    Wc[o*168 + kk] = (short)f2bf(w[o*160 + ((kk < 128) ? (32 + kk) : (kk - 128))]);
  }
  f32x4 acc[4][4];
  #pragma unroll
  for (int mf = 0; mf < 4; ++mf)
    #pragma unroll
    for (int nf = 0; nf < 4; ++nf)
      acc[mf][nf] = (f32x4){0.f, 0.f, 0.f, 0.f};
  for (int k0 = 0; k0 < 512; k0 += 64){
    __syncthreads();
    #pragma unroll
    for (int it = 0; it < 4; ++it){
      int r = it*32 + (tid>>3), g = tid & 7;
      gload16(A + (size_t)(rowBase + r)*512 + k0 + ((g ^ (r&7))<<3), AsL + r*64 + (g<<3));
      int s = r >> 5, nl = r & 31;
      gload16(Bb + (size_t)((s<<9) + n032 + nl)*512 + k0 + ((g ^ (r&7))<<3), BsL + r*64 + (g<<3));
    }
    __syncthreads();
    #pragma unroll
    for (int ks = 0; ks < 2; ++ks){
      bf16x8 af[4], bfr[4];
      #pragma unroll
      for (int mf = 0; mf < 4; ++mf){
        int rr = wm*64 + mf*16 + l15;
        af[mf] = *(const bf16x8*)(AsL + rr*64 + (((ks*4 + l4) ^ (rr & 7)) << 3));
      }
      #pragma unroll
      for (int nf = 0; nf < 4; ++nf){
        int rr = wn*64 + nf*16 + l15;
        bfr[nf] = *(const bf16x8*)(BsL + rr*64 + (((ks*4 + l4) ^ (rr & 7)) << 3));
      }
      #pragma unroll
      for (int mf = 0; mf < 4; ++mf)
        #pragma unroll
        for (int nf = 0; nf < 4; ++nf)
          acc[mf][nf] = __builtin_amdgcn_mfma_f32_16x16x32_bf16(af[mf], bfr[nf], acc[mf][nf], 0, 0, 0);
    }
  }
  const float inv = 1.0f / sqrtf(1.0f + 1e-5f);
  for (int t = 0; t < 4; ++t){
    __syncthreads();   // As/Bs (or prev Tt) free
    if (wm == (t >> 1)){
      #pragma unroll
      for (int mf2 = 0; mf2 < 2; ++mf2){
        int mf = (t & 1)*2 + mf2;
        #pragma unroll
        for (int nf = 0; nf < 4; ++nf){
          int c128 = wn*64 + nf*16 + l15;
          int s = c128 >> 5, nl = c128 & 31;
          #pragma unroll
          for (int r = 0; r < 4; ++r){
            int cROW = mf2*16 + l4*4 + r;
            Tt[nl*168 + s*32 + cROW] = (short)f2bf(acc[mf][nf][r]);
          }
        }
      }
    }
    // X^T chunk: cols 128..159 = A[c][n] transposed (the Wx term's input)
    for (int i = tid; i < 1024; i += 256){
      int c = i >> 5, nl = i & 31;
      Tt[nl*168 + 128 + c] =
        (short)A[(size_t)(b*Mb + (t0+t)*32 + c)*512 + n032 + nl];
    }
    __syncthreads();
    f32x4 am = (f32x4){0.f,0.f,0.f,0.f};
    #pragma unroll
    for (int ks = 0; ks < 5; ++ks){
      bf16x8 af = *(const bf16x8*)(Wc + (wm*16 + l15)*168 + ks*32 + l4*8);
      bf16x8 bf = *(const bf16x8*)(Tt + (wn*16 + l15)*168 + ks*32 + l4*8);
      am = __builtin_amdgcn_mfma_f32_16x16x32_bf16(af, bf, am, 0, 0, 0);
    }
    if (t0 + t < Tp){
      int btG = b*Tp + t0 + t;
      #pragma unroll
      for (int r = 0; r < 4; ++r){
        int o = wm*16 + l4*4 + r;
        int nl = wn*16 + l15;
        size_t oidx = (size_t)(btG*32 + o)*512 + n032 + nl;
        float val = am[r] + bias[o];
        if (outBf){
          outBf[oidx] = f2bf(val);
        } else {
          float resv = res[(size_t)((b*(Tp+dil) + t0 + t + dil)*32 + o)*512 + n032 + nl];
          outF[oidx] = (val + resv) * (bng[o]*inv) + bnb[o];
        }
      }
    }
  }
}

// ------- plain bf16 MFMA GEMM (used for end1): Y[m,n] = A[m,v]*BT[n,v] -------
__global__ __launch_bounds__(256) void k_gemm(
    const unsigned short* __restrict__ A, const unsigned short* __restrict__ BT,
    unsigned short* __restrict__ Y, int Mb, long long bStride,
    int K, int Ystride, int relu){
  __shared__ short As[128][64];
  __shared__ short Bs[128][64];
  int tid = threadIdx.x;
  int n0 = blockIdx.x * 128;
  int rowBase = blockIdx.z * Mb + blockIdx.y * 128;
  int rowEnd  = blockIdx.z * Mb + Mb;
  const unsigned short* Bb = BT + (size_t)blockIdx.z * bStride;
  int wid = tid >> 6, lane = tid & 63;
  int wm = wid >> 1, wn = wid & 1;
  int l15 = lane & 15, l4 = lane >> 4;
  f32x4 acc[4][4];
  #pragma unroll
  for (int mf = 0; mf < 4; ++mf)
    #pragma unroll
    for (int nf = 0; nf < 4; ++nf)
      acc[mf][nf] = (f32x4){0.f, 0.f, 0.f, 0.f};
  for (int k0 = 0; k0 < K; k0 += 64){
    __syncthreads();
    #pragma unroll
    for (int it = 0; it < 4; ++it){
      int r = it*32 + (tid>>3), g = tid & 7;
      gload16(A + (size_t)(rowBase + r)*K + k0 + ((g ^ (r&7))<<3), &As[r][g<<3]);
      gload16(Bb + (size_t)(n0 + r)*K + k0 + ((g ^ (r&7))<<3), &Bs[r][g<<3]);
    }
    __syncthreads();
    #pragma unroll
    for (int ks = 0; ks < 2; ++ks){
      bf16x8 af[4], bfr[4];
      #pragma unroll
      for (int mf = 0; mf < 4; ++mf){
        int r = wm*64 + mf*16 + l15;
        af[mf] = *(const bf16x8*)&As[r][(((ks*4 + l4) ^ (r & 7)) << 3)];
      }
      #pragma unroll
      for (int nf = 0; nf < 4; ++nf){
        int r = wn*64 + nf*16 + l15;
        bfr[nf] = *(const bf16x8*)&Bs[r][(((ks*4 + l4) ^ (r & 7)) << 3)];
      }
      #pragma unroll
      for (int mf = 0; mf < 4; ++mf)
        #pragma unroll
        for (int nf = 0; nf < 4; ++nf)
          acc[mf][nf] = __builtin_amdgcn_mfma_f32_16x16x32_bf16(af[mf], bfr[nf], acc[mf][nf], 0, 0, 0);
    }
  }
  #pragma unroll
  for (int mf = 0; mf < 4; ++mf){
    #pragma unroll
    for (int nf = 0; nf < 4; ++nf){
      #pragma unroll
      for (int r = 0; r < 4; ++r){
        int row = rowBase + wm*64 + mf*16 + l4*4 + r;
        if (row < rowEnd){
          int col = n0 + wn*64 + nf*16 + l15;
          float v = acc[mf][nf][r];
          if (relu) v = v > 0.f ? v : 0.f;
          Y[(size_t)row*Ystride + col] = f2bf(v);
        }
      }
    }
  }
}

// ---------------- skip -> relu -> bf16 transposed [(b,n), e] ----------------
__global__ __launch_bounds__(256) void k_skipT(const float* __restrict__ skip,
                                               unsigned short* __restrict__ skT){
  int b = blockIdx.z, e0 = blockIdx.y*64, n0 = blockIdx.x*64;
  __shared__ float Ts[64][65];
  int tid = threadIdx.x;
  for (int i = tid; i < 4096; i += 256){
    int r = i >> 6, c = i & 63;
    Ts[r][c] = skip[((size_t)b*SKC + e0 + r)*NNODE + n0 + c];
  }
  __syncthreads();
  for (int i = tid; i < 4096; i += 256){
    int r = i >> 6, c = i & 63;     // r = n-local, c = e-local
    float v = Ts[c][r];
    skT[((size_t)b*NNODE + n0 + r)*SKC + e0 + c] = f2bf(v > 0.f ? v : 0.f);
  }
}

// ---------------- fp32 -> bf16 weight converts ----------------
__global__ void k_cvt(const float* __restrict__ src, unsigned short* __restrict__ dst, int n){
  int i = blockIdx.x*256 + threadIdx.x;
  if (i < n) dst[i] = f2bf(src[i]);
}
__global__ void k_cvt_e2(const float* __restrict__ e2w, unsigned short* __restrict__ dst){
  int i = blockIdx.x*256 + threadIdx.x;   // 16*512
  if (i < 16*ENDC){
    int o = i >> 9;
    dst[i] = (o < ODIM) ? f2bf(e2w[(size_t)o*ENDC + (i & 511)]) : (unsigned short)0;
  }
}

// ---------------- end2: out[b,o,n] = e2b[o] + hid[(b,n),:]·e2w[o,:] ----------------
__global__ __launch_bounds__(256) void k_end2(const unsigned short* __restrict__ hid,
    const unsigned short* __restrict__ e2wB, const float* __restrict__ e2b,
    float* __restrict__ out){
  int rowBase = blockIdx.x * 64;
  int tid = threadIdx.x;
  int lane = tid & 63, w = tid >> 6;
  int l15 = lane & 15, l4 = lane >> 4;
  __shared__ unsigned short e2s[16][520];
  __shared__ float Cs[16][68];
  for (int i = tid; i < 4096; i += 256){
    int r = i >> 8, c2 = (i & 255) * 2;
    *(unsigned*)&e2s[r][c2] = *(const unsigned*)&e2wB[(size_t)r*ENDC + c2];
  }
  __syncthreads();
  f32x4 acc = (f32x4){0.f,0.f,0.f,0.f};
  const unsigned short* Ab = hid + (size_t)(rowBase + w*16 + l15)*ENDC;
  #pragma unroll
  for (int kk = 0; kk < 16; ++kk){
    bf16x8 af = *(const bf16x8*)(Ab + kk*32 + l4*8);
    bf16x8 bf = *(const bf16x8*)&e2s[l15][kk*32 + l4*8];
    acc = __builtin_amdgcn_mfma_f32_16x16x32_bf16(af, bf, acc, 0, 0, 0);
  }
  #pragma unroll
  for (int r = 0; r < 4; ++r)
    Cs[l15][w*16 + l4*4 + r] = acc[r];
  __syncthreads();
  for (int i = tid; i < ODIM*64; i += 256){
    int o = i >> 6, nl = i & 63;
    int gr = rowBase + nl;
    int b = gr >> 9, n = gr & 511;
    out[((size_t)(b*ODIM + o))*NNODE + n] = Cs[o][nl] + e2b[o];
  }
}

extern "C" void kernel_launch(void* const* d_in, const int* in_sizes, int n_in,
                              void* d_out, int out_size, void* d_ws, size_t ws_size,
                              hipStream_t stream){
  const float* input   = (const float*)d_in[0];
  const float* supports= (const float*)d_in[1];
  const float* emb     = (const float*)d_in[2];
  const float* embds_w = (const float*)d_in[3];
  const float* embds_b = (const float*)d_in[4];
  const float* wl_w    = (const float*)d_in[5];
  const float* wl_b    = (const float*)d_in[6];
  const float* wr_w    = (const float*)d_in[7];
  const float* wr_b    = (const float*)d_in[8];
  const float* start_w = (const float*)d_in[9];
  const float* start_b = (const float*)d_in[10];
  const float* filter_w= (const float*)d_in[11];
  const float* filter_b= (const float*)d_in[12];
  const float* gate_w  = (const float*)d_in[13];
  const float* gate_b  = (const float*)d_in[14];
  const float* skip_w  = (const float*)d_in[15];
  const float* skip_b  = (const float*)d_in[16];
  const float* bn_g    = (const float*)d_in[17];
  const float* bn_b    = (const float*)d_in[18];
  const float* gconv_w = (const float*)d_in[19];
  const float* gconv_b = (const float*)d_in[20];
  const float* dyn_w   = (const float*)d_in[21];
  const float* dyn_b   = (const float*)d_in[22];
  const float* end1_w  = (const float*)d_in[23];
  const float* end1_b  = (const float*)d_in[24];
  const float* end2_w  = (const float*)d_in[25];
  const float* end2_b  = (const float*)d_in[26];
  float* out = (float*)d_out;

  float* ws = (float*)d_ws;
  // ---- Region R0: 33,554,432 floats. Prologue: fp32 att (becomes bf16 in place).
  //      Loop phase: act | bufP | bufQ | skip | R.
  float* dyn = ws;
  unsigned short* act = (unsigned short*)ws;                 // 3,145,728 floats
  float* bufP = ws + 3145728;                                // 6,815,744
  float* bufQ = ws + 3145728 + 6815744;                      // 6,815,744
  float* skip = ws + 16777216;                               // 4,194,304
  unsigned short* R = (unsigned short*)(ws + 20971520);      // 3,145,728 floats (in old Y region)
  // ---- dynT region: 16,777,216 floats (33,554,432 bf16). Prologue alias: l/r.
  unsigned short* dynT = (unsigned short*)(ws + 33554432);
  float* lbuf = ws + 33554432;                               // 2,097,152 (alias)
  float* rbuf = ws + 33554432 + 2097152;                     // 2,097,152 (alias)
  // ---- supT: 524,288 floats.
  unsigned short* supT = (unsigned short*)(ws + 33554432 + 16777216);
  // ---- end-MLP buffers (used only after the layer loop):
  unsigned short* skT  = (unsigned short*)(ws + 50855936);   // 2,097,152 floats
  unsigned short* hid  = (unsigned short*)(ws + 52953088);   // 4,194,304 floats
  unsigned short* e1wB = (unsigned short*)(ws + 57147392);   //    65,536 floats
  unsigned short* e2wB = (unsigned short*)(ws + 57212928);   //     4,096 floats
  // total: 57,217,024 floats = 228.9 MB (proven-safe)

  hipLaunchKernelGGL(k_feat_lr, dim3(BB*NNODE), dim3(128), 0, stream,
                     input, emb, embds_w, embds_b, wl_w, wl_b, wr_w, wr_b, lbuf, rbuf);
  hipLaunchKernelGGL(k_att, dim3(16, 16, BB*NH), dim3(256), 0, stream, lbuf, rbuf, dyn);
  hipLaunchKernelGGL(k_topk_softmax, dim3(BB*NH*NNODE/4), dim3(256), 0, stream, dyn);
  hipLaunchKernelGGL(k_transpose_dyn, dim3(8, 8, BB*NH), dim3(256), 0, stream,
                     (const unsigned short*)dyn, dynT);
  hipLaunchKernelGGL(k_supT_copy, dim3(8, 8, 2), dim3(256), 0, stream, supports, supT);
  hipLaunchKernelGGL(k_supT_sq, dim3(16, 16, 2), dim3(256), 0, stream, supports, supT);
  {
    int total = BB*RFP*CCH*NNODE;
    hipLaunchKernelGGL(k_make_x0, dim3((total+255)/256), dim3(256), 0, stream,
                       input, start_w, start_b, bufP);
  }

  const int dil_[8] = {1,2,1,2,1,2,1,2};
  int T = RFP;
  float* P = bufP; float* Q = bufQ;
  for (int i = 0; i < NL; ++i){
    int d = dil_[i], Tp = T - d;
    int mT = (Tp*32 + 127)/128;
    hipLaunchKernelGGL(k_dconv_act, dim3(Tp, BB), dim3(512), 0, stream,
        P, filter_w + i*2048, filter_b + i*32, gate_w + i*2048, gate_b + i*32,
        act, T, Tp, d);
    hipLaunchKernelGGL(k_skip_accum, dim3(8, 8, BB), dim3(256), 0, stream,
        act, skip_w + i*SKC*CCH, skip_b + i*SKC, skip, Tp, (i==0)?1:0);
    // dyn GCN + mix -> R (bf16)
    hipLaunchKernelGGL(k_gcn_gemm, dim3(16, mT, BB), dim3(256), 0, stream,
        act, dynT, dyn_w + i*5120, dyn_b + i*32,
        R, (float*)nullptr, (const float*)nullptr, (const float*)nullptr,
        (const float*)nullptr, Tp, d, (long long)NH*NNODE*NNODE);
    // sup GCN + mix + residual + bn -> Q (fp32)
    hipLaunchKernelGGL(k_gcn_gemm, dim3(16, mT, BB), dim3(256), 0, stream,
        R, supT, gconv_w + i*5120, gconv_b + i*32,
        (unsigned short*)nullptr, Q, P, bn_g + i*32, bn_b + i*32, Tp, d, 0LL);
    float* tmp = P; P = Q; Q = tmp;
    T = Tp;
  }
  // ---- end MLP: skipT -> MFMA end1 (relu) -> MFMA end2 ----
  hipLaunchKernelGGL(k_skipT, dim3(8, 4, BB), dim3(256), 0, stream, skip, skT);
  hipLaunchKernelGGL(k_cvt, dim3((ENDC*SKC+255)/256), dim3(256), 0, stream,
                     end1_w, e1wB, ENDC*SKC);
  hipLaunchKernelGGL(k_cvt_e2, dim3((16*ENDC+255)/256), dim3(256), 0, stream,
                     end2_w, e2wB);
  hipLaunchKernelGGL(k_gemm, dim3(4, 128, 1), dim3(256), 0, stream,
      skT, e1wB, hid, BB*NNODE, 0LL, 256, 512, 1);
  hipLaunchKernelGGL(k_end2, dim3(256), dim3(256), 0, stream, hid, e2wB, end1_b, out);
}